// Round 1
// baseline (334.311 us; speedup 1.0000x reference)
//
#include <hip/hip_runtime.h>

// Multi-hot encode: out[n, t, x[n, t, f]] = 1.0, everything else 0.
// x: [32, 512, 10] int32, out: [32, 512, 5000] fp32.
// Write-BW bound: ~328 MB of output per call (harness poisons d_out to 0xAA
// before every timed launch, so we must zero it ourselves each call).

#define NUM_TOKENS 5000
#define NFEAT 10

// One block per (n, t) row. Zero the 5000-float row with float4 stores,
// barrier, then 10 threads scatter the 1.0s. Block owns the row -> no
// atomics, no inter-block ordering assumptions.
__global__ __launch_bounds__(256) void tenhot_kernel(const int* __restrict__ x,
                                                     float* __restrict__ out) {
    const int row = blockIdx.x;                      // n*T + t, 0..16383
    float* __restrict__ row_ptr = out + (size_t)row * NUM_TOKENS;

    // Row stride = 5000 floats = 20000 B, divisible by 16 -> float4 aligned.
    float4* __restrict__ row4 = reinterpret_cast<float4*>(row_ptr);
    const float4 z = {0.f, 0.f, 0.f, 0.f};
    for (int i = threadIdx.x; i < NUM_TOKENS / 4; i += 256) {
        row4[i] = z;
    }

    __syncthreads();  // drain zero-stores before scatter (intra-block ordering)

    if (threadIdx.x < NFEAT) {
        const int idx = x[row * NFEAT + threadIdx.x];
        row_ptr[idx] = 1.0f;
    }
}

extern "C" void kernel_launch(void* const* d_in, const int* in_sizes, int n_in,
                              void* d_out, int out_size, void* d_ws, size_t ws_size,
                              hipStream_t stream) {
    const int* x = (const int*)d_in[0];
    float* out = (float*)d_out;
    const int n_rows = in_sizes[0] / NFEAT;  // 32*512 = 16384
    tenhot_kernel<<<n_rows, 256, 0, stream>>>(x, out);
}